// Round 1
// baseline (805.805 us; speedup 1.0000x reference)
//
#include <hip/hip_runtime.h>

typedef __attribute__((ext_vector_type(8))) short s16x8;
typedef __attribute__((ext_vector_type(8))) unsigned short u16x8;
typedef __attribute__((ext_vector_type(4))) unsigned short u16x4;
typedef __attribute__((ext_vector_type(4))) float f32x4;

__device__ inline float bf2f(unsigned short h) {
  union { unsigned int u; float f; } x; x.u = ((unsigned int)h) << 16; return x.f;
}
__device__ inline unsigned short f2bf(float f) {
  union { float f; unsigned int u; } x; x.f = f;
  unsigned int u = x.u;
  return (unsigned short)((u + 0x7fffu + ((u >> 16) & 1u)) >> 16);
}

// ---------------------------------------------------------------------------
// f32 -> bf16 cast with output row remap (ldo may exceed cols for the fused
// buffer's left half). cols = 1<<shift, multiple of 8.
// ---------------------------------------------------------------------------
__global__ __launch_bounds__(256) void cvt_bf16(const float* __restrict__ in,
                                                unsigned short* __restrict__ out,
                                                long long n, int shift, int ldo) {
  long long i = (long long)blockIdx.x * 256 + threadIdx.x;
  long long stride = (long long)gridDim.x * 256;
  long long nchunks = n >> 3;
  for (; i < nchunks; i += stride) {
    long long e = i << 3;
    long long r = e >> shift;
    int c = (int)(e & ((1LL << shift) - 1));
    const float4* p = (const float4*)(in + e);
    float4 f0 = p[0], f1 = p[1];
    u16x8 u;
    u[0] = f2bf(f0.x); u[1] = f2bf(f0.y); u[2] = f2bf(f0.z); u[3] = f2bf(f0.w);
    u[4] = f2bf(f1.x); u[5] = f2bf(f1.y); u[6] = f2bf(f1.z); u[7] = f2bf(f1.w);
    *(u16x8*)&out[r * (long long)ldo + c] = u;
  }
}

// ---------------------------------------------------------------------------
// per-batch bf16 transpose: in [rows][cols] -> out [cols][rows], 64x64 tiles
// ---------------------------------------------------------------------------
__global__ __launch_bounds__(256) void transpose_bf16(const unsigned short* __restrict__ in,
                                                      unsigned short* __restrict__ out,
                                                      int rows, int cols) {
  __shared__ unsigned short tile[64][72];  // 72: keeps 8B alignment of rows
  long long zoff = (long long)blockIdx.z * rows * cols;
  const unsigned short* src = in + zoff;
  unsigned short* dst = out + zoff;
  int k0 = blockIdx.x * 64, d0 = blockIdx.y * 64;
  int t = threadIdx.x;
  int rr = t >> 4;          // 0..15
  int cc = (t & 15) * 4;    // 0..60
#pragma unroll
  for (int i = 0; i < 4; ++i) {
    int k = rr + i * 16;
    u16x4 v = *(const u16x4*)&src[(long long)(k0 + k) * cols + d0 + cc];
    *(u16x4*)&tile[k][cc] = v;
  }
  __syncthreads();
#pragma unroll
  for (int i = 0; i < 4; ++i) {
    int d = rr + i * 16;
    u16x4 v;
#pragma unroll
    for (int j = 0; j < 4; ++j) v[j] = tile[cc + j][d];
    *(u16x4*)&dst[(long long)(d0 + d) * rows + k0 + cc] = v;
  }
}

// ---------------------------------------------------------------------------
// row softmax over 2048 bf16 elements, in place; one wave per row
// ---------------------------------------------------------------------------
__global__ __launch_bounds__(256) void softmax_rows(unsigned short* __restrict__ P) {
  int w = threadIdx.x >> 6, l = threadIdx.x & 63;
  long long row = (long long)blockIdx.x * 4 + w;
  unsigned short* p = P + row * 2048;
  float v[32];
  float m = -1e30f;
#pragma unroll
  for (int c = 0; c < 4; ++c) {
    u16x8 u = *(const u16x8*)&p[c * 512 + l * 8];
#pragma unroll
    for (int j = 0; j < 8; ++j) { v[c * 8 + j] = bf2f(u[j]); m = fmaxf(m, v[c * 8 + j]); }
  }
#pragma unroll
  for (int s = 32; s; s >>= 1) m = fmaxf(m, __shfl_xor(m, s));
  float sum = 0.f;
#pragma unroll
  for (int i = 0; i < 32; ++i) { v[i] = __expf(v[i] - m); sum += v[i]; }
#pragma unroll
  for (int s = 32; s; s >>= 1) sum += __shfl_xor(sum, s);
  float r = 1.0f / sum;
#pragma unroll
  for (int c = 0; c < 4; ++c) {
    u16x8 u;
#pragma unroll
    for (int j = 0; j < 8; ++j) u[j] = f2bf(v[c * 8 + j] * r);
    *(u16x8*)&p[c * 512 + l * 8] = u;
  }
}

// ---------------------------------------------------------------------------
// 128x128 bf16 GEMM, B^T layout: C[m][n] = sum_k A[m][k] * Bt[n][k]
// m97 structure: BK=32, 4 waves, global_load_lds width 16, 16x16x32 MFMA.
// out = (acc + bias[col]) * scale.  Optional batch via blockIdx.z strides.
// ---------------------------------------------------------------------------
template <bool OUT_BF16, bool HAS_BIAS>
__global__ __launch_bounds__(256, 2) void gemm_bt(
    const unsigned short* __restrict__ A, const unsigned short* __restrict__ Bt,
    void* __restrict__ C, const float* __restrict__ bias,
    int K, int lda, int ldb, int ldc,
    long long sA, long long sB, long long sC, float scale) {
  __shared__ unsigned short As[128 * 32];
  __shared__ unsigned short Bs[128 * 32];
  const int t = threadIdx.x;
  const int w = t >> 6, l = t & 63;
  const int wr = w >> 1, wc = w & 1;
  const long long zb = blockIdx.z;
  A += zb * sA;
  Bt += zb * sB;
  const long long m0 = (long long)blockIdx.y * 128;
  const long long n0 = (long long)blockIdx.x * 128;

  f32x4 acc[4][4] = {};

  const int j0 = w * 2;
  const int r_a = (l >> 2);      // row within 16-row stripe
  const int c8 = (l & 3) * 8;    // 8-elem segment within BK=32

  for (int kt = 0; kt < K; kt += 32) {
    __syncthreads();
#pragma unroll
    for (int i = 0; i < 2; ++i) {
      int j = j0 + i;
      const unsigned short* ga = A + (m0 + j * 16 + r_a) * lda + (kt + c8);
      __builtin_amdgcn_global_load_lds(
          (const __attribute__((address_space(1))) void*)ga,
          (__attribute__((address_space(3))) void*)(As + j * 512), 16, 0, 0);
      const unsigned short* gb = Bt + (n0 + j * 16 + r_a) * ldb + (kt + c8);
      __builtin_amdgcn_global_load_lds(
          (const __attribute__((address_space(1))) void*)gb,
          (__attribute__((address_space(3))) void*)(Bs + j * 512), 16, 0, 0);
    }
    __syncthreads();
    const int rr = (l & 15);
    const int kk = (l >> 4) * 8;
    s16x8 af[4], bf[4];
#pragma unroll
    for (int mi = 0; mi < 4; ++mi)
      af[mi] = *(const s16x8*)&As[(wr * 64 + mi * 16 + rr) * 32 + kk];
#pragma unroll
    for (int ni = 0; ni < 4; ++ni)
      bf[ni] = *(const s16x8*)&Bs[(wc * 64 + ni * 16 + rr) * 32 + kk];
#pragma unroll
    for (int mi = 0; mi < 4; ++mi)
#pragma unroll
      for (int ni = 0; ni < 4; ++ni)
        acc[mi][ni] = __builtin_amdgcn_mfma_f32_16x16x32_bf16(af[mi], bf[ni], acc[mi][ni], 0, 0, 0);
  }

  const int cl = l & 15, rg = (l >> 4) * 4;
#pragma unroll
  for (int mi = 0; mi < 4; ++mi) {
#pragma unroll
    for (int ni = 0; ni < 4; ++ni) {
      long long col = n0 + wc * 64 + ni * 16 + cl;
      long long row = m0 + wr * 64 + mi * 16 + rg;
      float bb = HAS_BIAS ? bias[col] : 0.0f;
#pragma unroll
      for (int jj = 0; jj < 4; ++jj) {
        float v = (acc[mi][ni][jj] + bb) * scale;
        if (OUT_BF16)
          ((unsigned short*)C)[zb * sC + (row + jj) * ldc + col] = f2bf(v);
        else
          ((float*)C)[zb * sC + (row + jj) * ldc + col] = v;
      }
    }
  }
}

// ---------------------------------------------------------------------------
// Host launcher.
// ws layout (bytes):
//   fused  [32768][2048] bf16 : 0          .. 134217728   (bert | attn_out)
//   bfq    [32768][1024] bf16 : 134217728  .. 201326592
//   know16 [16][2048][1024]   : 201326592  .. 268435456
//   knowT  [16][1024][2048]   : 268435456  .. 335544320
//   w1_16  [1024][1024]       : 335544320  .. 337641472
//   w2_16  [1024][2048]       : 337641472  .. 341835776
// P (scores/probs) lives in d_out (bf16, exactly out_size*4 bytes), then
// d_out is overwritten by the final fusion GEMM (f32).
// ---------------------------------------------------------------------------
extern "C" void kernel_launch(void* const* d_in, const int* in_sizes, int n_in,
                              void* d_out, int out_size, void* d_ws, size_t ws_size,
                              hipStream_t stream) {
  const float* bert = (const float*)d_in[0];
  const float* know = (const float*)d_in[1];
  const float* w1w  = (const float*)d_in[2];
  const float* w1b  = (const float*)d_in[3];
  const float* w2w  = (const float*)d_in[4];
  const float* w2b  = (const float*)d_in[5];

  char* ws = (char*)d_ws;
  unsigned short* fused  = (unsigned short*)(ws);
  unsigned short* bfq    = (unsigned short*)(ws + 134217728LL);
  unsigned short* know16 = (unsigned short*)(ws + 201326592LL);
  unsigned short* knowT  = (unsigned short*)(ws + 268435456LL);
  unsigned short* w1_16  = (unsigned short*)(ws + 335544320LL);
  unsigned short* w2_16  = (unsigned short*)(ws + 337641472LL);
  unsigned short* P      = (unsigned short*)d_out;

  // casts
  cvt_bf16<<<2048, 256, 0, stream>>>(bert, fused, 33554432LL, 10, 2048);
  cvt_bf16<<<2048, 256, 0, stream>>>(know, know16, 33554432LL, 10, 1024);
  cvt_bf16<<<512, 256, 0, stream>>>(w1w, w1_16, 1048576LL, 10, 1024);
  cvt_bf16<<<512, 256, 0, stream>>>(w2w, w2_16, 2097152LL, 11, 2048);
  transpose_bf16<<<dim3(32, 16, 16), 256, 0, stream>>>(know16, knowT, 2048, 1024);

  // 1) bfq = (bert @ w1^T + b1) / 32          M=32768 N=1024 K=1024
  gemm_bt<true, true><<<dim3(8, 256, 1), 256, 0, stream>>>(
      fused, w1_16, bfq, w1b, 1024, 2048, 1024, 1024, 0, 0, 0, 0.03125f);

  // 2) P = bfq @ know^T  (per batch)          M=2048 N=2048 K=1024
  gemm_bt<true, false><<<dim3(16, 16, 16), 256, 0, stream>>>(
      bfq, know16, P, nullptr, 1024, 1024, 1024, 2048,
      2048LL * 1024, 2048LL * 1024, 2048LL * 2048, 1.0f);

  // 3) softmax rows of P, in place
  softmax_rows<<<8192, 256, 0, stream>>>(P);

  // 4) attn_out = P @ know  (per batch)       M=2048 N=1024 K=2048
  gemm_bt<true, false><<<dim3(8, 16, 16), 256, 0, stream>>>(
      P, knowT, fused + 1024, nullptr, 2048, 2048, 2048, 2048,
      2048LL * 2048, 1024LL * 2048, 2048LL * 2048, 1.0f);

  // 5) out = fused @ w2^T + b2  (f32)         M=32768 N=1024 K=2048
  gemm_bt<false, true><<<dim3(8, 256, 1), 256, 0, stream>>>(
      fused, w2_16, d_out, w2b, 2048, 2048, 2048, 1024, 0, 0, 0, 1.0f);
}

// Round 2
// 650.113 us; speedup vs baseline: 1.2395x; 1.2395x over previous
//
#include <hip/hip_runtime.h>

typedef __attribute__((ext_vector_type(8))) short s16x8;
typedef __attribute__((ext_vector_type(8))) unsigned short u16x8;
typedef __attribute__((ext_vector_type(4))) unsigned short u16x4;
typedef __attribute__((ext_vector_type(4))) float f32x4;

__device__ inline float bf2f(unsigned short h) {
  union { unsigned int u; float f; } x; x.u = ((unsigned int)h) << 16; return x.f;
}
__device__ inline unsigned short f2bf(float f) {
  union { float f; unsigned int u; } x; x.f = f;
  unsigned int u = x.u;
  return (unsigned short)((u + 0x7fffu + ((u >> 16) & 1u)) >> 16);
}

// ---------------------------------------------------------------------------
// f32 -> bf16 cast with output row remap. cols = 1<<shift, multiple of 8.
// ---------------------------------------------------------------------------
__global__ __launch_bounds__(256) void cvt_bf16(const float* __restrict__ in,
                                                unsigned short* __restrict__ out,
                                                long long n, int shift, int ldo) {
  long long i = (long long)blockIdx.x * 256 + threadIdx.x;
  long long stride = (long long)gridDim.x * 256;
  long long nchunks = n >> 3;
  for (; i < nchunks; i += stride) {
    long long e = i << 3;
    long long r = e >> shift;
    int c = (int)(e & ((1LL << shift) - 1));
    const float4* p = (const float4*)(in + e);
    float4 f0 = p[0], f1 = p[1];
    u16x8 u;
    u[0] = f2bf(f0.x); u[1] = f2bf(f0.y); u[2] = f2bf(f0.z); u[3] = f2bf(f0.w);
    u[4] = f2bf(f1.x); u[5] = f2bf(f1.y); u[6] = f2bf(f1.z); u[7] = f2bf(f1.w);
    *(u16x8*)&out[r * (long long)ldo + c] = u;
  }
}

// ---------------------------------------------------------------------------
// per-batch bf16 transpose: in [rows][cols] -> out [cols][rows], 64x64 tiles
// ---------------------------------------------------------------------------
__global__ __launch_bounds__(256) void transpose_bf16(const unsigned short* __restrict__ in,
                                                      unsigned short* __restrict__ out,
                                                      int rows, int cols) {
  __shared__ unsigned short tile[64][72];
  long long zoff = (long long)blockIdx.z * rows * cols;
  const unsigned short* src = in + zoff;
  unsigned short* dst = out + zoff;
  int k0 = blockIdx.x * 64, d0 = blockIdx.y * 64;
  int t = threadIdx.x;
  int rr = t >> 4;
  int cc = (t & 15) * 4;
#pragma unroll
  for (int i = 0; i < 4; ++i) {
    int k = rr + i * 16;
    u16x4 v = *(const u16x4*)&src[(long long)(k0 + k) * cols + d0 + cc];
    *(u16x4*)&tile[k][cc] = v;
  }
  __syncthreads();
#pragma unroll
  for (int i = 0; i < 4; ++i) {
    int d = rr + i * 16;
    u16x4 v;
#pragma unroll
    for (int j = 0; j < 4; ++j) v[j] = tile[cc + j][d];
    *(u16x4*)&dst[(long long)(d0 + d) * rows + k0 + cc] = v;
  }
}

// ---------------------------------------------------------------------------
// row softmax over 2048 bf16 elements, in place; one wave per row
// ---------------------------------------------------------------------------
__global__ __launch_bounds__(256) void softmax_rows(unsigned short* __restrict__ P) {
  int w = threadIdx.x >> 6, l = threadIdx.x & 63;
  long long row = (long long)blockIdx.x * 4 + w;
  unsigned short* p = P + row * 2048;
  float v[32];
  float m = -1e30f;
#pragma unroll
  for (int c = 0; c < 4; ++c) {
    u16x8 u = *(const u16x8*)&p[c * 512 + l * 8];
#pragma unroll
    for (int j = 0; j < 8; ++j) { v[c * 8 + j] = bf2f(u[j]); m = fmaxf(m, v[c * 8 + j]); }
  }
#pragma unroll
  for (int s = 32; s; s >>= 1) m = fmaxf(m, __shfl_xor(m, s));
  float sum = 0.f;
#pragma unroll
  for (int i = 0; i < 32; ++i) { v[i] = __expf(v[i] - m); sum += v[i]; }
#pragma unroll
  for (int s = 32; s; s >>= 1) sum += __shfl_xor(sum, s);
  float r = 1.0f / sum;
#pragma unroll
  for (int c = 0; c < 4; ++c) {
    u16x8 u;
#pragma unroll
    for (int j = 0; j < 8; ++j) u[j] = f2bf(v[c * 8 + j] * r);
    *(u16x8*)&p[c * 512 + l * 8] = u;
  }
}

// ---------------------------------------------------------------------------
// 256x256 bf16 GEMM, B^T layout: C[m][n] = sum_k A[m][k]*Bt[n][k]
// Ring-4 pipelined: BK=32, 8 waves (2m x 4n, each 128x64 out), LDS 128 KiB
// (4 slots x [A 16KB | B 16KB]), stage tile t+3 while computing tile t,
// counted vmcnt(8) boundary (never 0 mid-loop), raw s_barrier, setprio
// around MFMA clusters, 16x32-subtiled LDS with row-XOR swizzle, XCD-aware
// block swizzle. All LDS writes are global_load_lds DMA (no ds_write).
// Requires: M%256==0, N%256==0, K%32==0, K>=128, grid%8==0.
// ---------------------------------------------------------------------------
template <bool OUT_BF16, bool HAS_BIAS>
__global__ __launch_bounds__(512, 1) void gemm256(
    const unsigned short* __restrict__ A, const unsigned short* __restrict__ Bt,
    void* __restrict__ C, const float* __restrict__ bias,
    int K, int lda, int ldb, int ldc,
    long long sA, long long sB, long long sC, float scale,
    int gx, int gy) {
  __shared__ char lds[131072];
  const int t = threadIdx.x;
  const int l = t & 63, w = t >> 6;
  const int wm = w >> 2, wn = w & 3;

  // XCD-aware swizzle (launcher guarantees gridDim.x % 8 == 0)
  const int nwg = gridDim.x;
  const int id = blockIdx.x;
  const int sid = (id & 7) * (nwg >> 3) + (id >> 3);
  const int bx = sid % gx;
  const int rem = sid / gx;
  const int by = rem % gy;
  const int bz = rem / gy;

  A += (long long)bz * sA;
  Bt += (long long)bz * sB;
  const long long m0 = (long long)by * 256;
  const long long n0 = (long long)bx * 256;

  // --- staging address precompute (per thread) ---
  // LDS unit-half: L = t*16 (u=0) / 8192 + t*16 (u=1), linear dest.
  // logical (row,k) whose swizzled home is L:  row = u*128 + (t>>2),
  // k_byte = ((t&3)*16) ^ (((t>>3)&3)<<4).
  const int srow = t >> 2;
  const int sk = (((t & 3) * 16) ^ (((t >> 3) & 3) << 4)) >> 1;
  const unsigned short* ga0 = A + (m0 + srow) * lda + sk;
  const unsigned short* ga1 = A + (m0 + 128 + srow) * lda + sk;
  const unsigned short* gb0 = Bt + (n0 + srow) * ldb + sk;
  const unsigned short* gb1 = Bt + (n0 + 128 + srow) * ldb + sk;
  const int Lt = t * 16;

  // --- fragment-read lane offset (within a 1024B 16x32 subtile) ---
  // phys = (l&15)*64 + (((l>>4)*16) ^ (((l>>1)&3)<<4))
  const int laneoff = (l & 15) * 64 + ((((l >> 4) * 16)) ^ (((l >> 1) & 3) << 4));

  f32x4 acc[8][4] = {};
  const int nt = K >> 5;

#define STAGE_A(tt)                                                                  \
  {                                                                                  \
    char* s_ = lds + (((tt) & 3) * 32768);                                           \
    long long ko_ = (long long)(tt) * 32;                                            \
    __builtin_amdgcn_global_load_lds(                                                \
        (const __attribute__((address_space(1))) void*)(ga0 + ko_),                  \
        (__attribute__((address_space(3))) void*)(s_ + Lt), 16, 0, 0);               \
    __builtin_amdgcn_global_load_lds(                                                \
        (const __attribute__((address_space(1))) void*)(ga1 + ko_),                  \
        (__attribute__((address_space(3))) void*)(s_ + 8192 + Lt), 16, 0, 0);        \
  }
#define STAGE_B(tt)                                                                  \
  {                                                                                  \
    char* s_ = lds + (((tt) & 3) * 32768) + 16384;                                   \
    long long ko_ = (long long)(tt) * 32;                                            \
    __builtin_amdgcn_global_load_lds(                                                \
        (const __attribute__((address_space(1))) void*)(gb0 + ko_),                  \
        (__attribute__((address_space(3))) void*)(s_ + Lt), 16, 0, 0);               \
    __builtin_amdgcn_global_load_lds(                                                \
        (const __attribute__((address_space(1))) void*)(gb1 + ko_),                  \
        (__attribute__((address_space(3))) void*)(s_ + 8192 + Lt), 16, 0, 0);        \
  }

  // prologue: tiles 0,1,2 staged; retire tile 0 (keep 8 = tiles 1,2)
  STAGE_A(0); STAGE_B(0);
  STAGE_A(1); STAGE_B(1);
  STAGE_A(2); STAGE_B(2);
  asm volatile("s_waitcnt vmcnt(8)" ::: "memory");
  __builtin_amdgcn_s_barrier();

  for (int tt = 0; tt < nt; ++tt) {
    const char* sa = lds + ((tt & 3) * 32768) + wm * 8192;
    const char* sb = lds + ((tt & 3) * 32768) + 16384 + wn * 4096;
    s16x8 af[4], bf[4];
    // ---- phase A: read A m0-3 + B n0-3, stage A(t+3), MFMA quadrant 0 ----
#pragma unroll
    for (int m = 0; m < 4; ++m) af[m] = *(const s16x8*)(sa + m * 1024 + laneoff);
#pragma unroll
    for (int n = 0; n < 4; ++n) bf[n] = *(const s16x8*)(sb + n * 1024 + laneoff);
    if (tt + 3 < nt) STAGE_A(tt + 3);
    __builtin_amdgcn_s_barrier();
    __builtin_amdgcn_s_setprio(1);
#pragma unroll
    for (int m = 0; m < 4; ++m)
#pragma unroll
      for (int n = 0; n < 4; ++n)
        acc[m][n] = __builtin_amdgcn_mfma_f32_16x16x32_bf16(af[m], bf[n], acc[m][n], 0, 0, 0);
    __builtin_amdgcn_s_setprio(0);
    __builtin_amdgcn_s_barrier();
    // ---- phase B: read A m4-7, stage B(t+3), MFMA quadrant 1 ----
#pragma unroll
    for (int m = 0; m < 4; ++m) af[m] = *(const s16x8*)(sa + (4 + m) * 1024 + laneoff);
    if (tt + 3 < nt) STAGE_B(tt + 3);
    __builtin_amdgcn_s_barrier();
    __builtin_amdgcn_s_setprio(1);
#pragma unroll
    for (int m = 0; m < 4; ++m)
#pragma unroll
      for (int n = 0; n < 4; ++n)
        acc[4 + m][n] = __builtin_amdgcn_mfma_f32_16x16x32_bf16(af[m], bf[n], acc[4 + m][n], 0, 0, 0);
    __builtin_amdgcn_s_setprio(0);
    // ---- boundary: retire everything except tiles > tt+1 ----
    const int ahead = nt - tt - 2;  // staged tiles beyond tt+1 (effectively capped at 2)
    if (ahead >= 2)      asm volatile("s_waitcnt vmcnt(8)" ::: "memory");
    else if (ahead == 1) asm volatile("s_waitcnt vmcnt(4)" ::: "memory");
    else                 asm volatile("s_waitcnt vmcnt(0)" ::: "memory");
    __builtin_amdgcn_s_barrier();
  }
#undef STAGE_A
#undef STAGE_B

  // ---- epilogue: C write ----
  const int cl = l & 15, rg = (l >> 4) * 4;
#pragma unroll
  for (int m = 0; m < 8; ++m) {
#pragma unroll
    for (int n = 0; n < 4; ++n) {
      long long col = n0 + wn * 64 + n * 16 + cl;
      long long row = m0 + wm * 128 + m * 16 + rg;
      float bb = HAS_BIAS ? bias[col] : 0.0f;
#pragma unroll
      for (int j = 0; j < 4; ++j) {
        float v = (acc[m][n][j] + bb) * scale;
        if (OUT_BF16)
          ((unsigned short*)C)[bz * sC + (row + j) * ldc + col] = f2bf(v);
        else
          ((float*)C)[bz * sC + (row + j) * ldc + col] = v;
      }
    }
  }
}

// ---------------------------------------------------------------------------
// Host launcher. ws layout (bytes):
//   fused  [32768][2048] bf16 : 0          .. 134217728   (bert | attn_out)
//   bfq    [32768][1024] bf16 : 134217728  .. 201326592
//   know16 [16][2048][1024]   : 201326592  .. 268435456
//   knowT  [16][1024][2048]   : 268435456  .. 335544320
//   w1_16  [1024][1024]       : 335544320  .. 337641472
//   w2_16  [1024][2048]       : 337641472  .. 341835776
// P (scores/probs) lives in d_out (bf16), then d_out is overwritten by the
// final fusion GEMM (f32).
// ---------------------------------------------------------------------------
extern "C" void kernel_launch(void* const* d_in, const int* in_sizes, int n_in,
                              void* d_out, int out_size, void* d_ws, size_t ws_size,
                              hipStream_t stream) {
  const float* bert = (const float*)d_in[0];
  const float* know = (const float*)d_in[1];
  const float* w1w  = (const float*)d_in[2];
  const float* w1b  = (const float*)d_in[3];
  const float* w2w  = (const float*)d_in[4];
  const float* w2b  = (const float*)d_in[5];

  char* ws = (char*)d_ws;
  unsigned short* fused  = (unsigned short*)(ws);
  unsigned short* bfq    = (unsigned short*)(ws + 134217728LL);
  unsigned short* know16 = (unsigned short*)(ws + 201326592LL);
  unsigned short* knowT  = (unsigned short*)(ws + 268435456LL);
  unsigned short* w1_16  = (unsigned short*)(ws + 335544320LL);
  unsigned short* w2_16  = (unsigned short*)(ws + 337641472LL);
  unsigned short* P      = (unsigned short*)d_out;

  // casts
  cvt_bf16<<<2048, 256, 0, stream>>>(bert, fused, 33554432LL, 10, 2048);
  cvt_bf16<<<2048, 256, 0, stream>>>(know, know16, 33554432LL, 10, 1024);
  cvt_bf16<<<512, 256, 0, stream>>>(w1w, w1_16, 1048576LL, 10, 1024);
  cvt_bf16<<<512, 256, 0, stream>>>(w2w, w2_16, 2097152LL, 11, 2048);
  transpose_bf16<<<dim3(32, 16, 16), 256, 0, stream>>>(know16, knowT, 2048, 1024);

  // 1) bfq = (bert @ w1^T + b1) / 32          M=32768 N=1024 K=1024
  gemm256<true, true><<<4 * 128, 512, 0, stream>>>(
      fused, w1_16, bfq, w1b, 1024, 2048, 1024, 1024, 0, 0, 0, 0.03125f, 4, 128);

  // 2) P = bfq @ know^T  (per batch)          M=2048 N=2048 K=1024
  gemm256<true, false><<<8 * 8 * 16, 512, 0, stream>>>(
      bfq, know16, P, nullptr, 1024, 1024, 1024, 2048,
      2048LL * 1024, 2048LL * 1024, 2048LL * 2048, 1.0f, 8, 8);

  // 3) softmax rows of P, in place
  softmax_rows<<<8192, 256, 0, stream>>>(P);

  // 4) attn_out = P @ know  (per batch)       M=2048 N=1024 K=2048
  gemm256<true, false><<<4 * 8 * 16, 512, 0, stream>>>(
      P, knowT, fused + 1024, nullptr, 2048, 2048, 2048, 2048,
      2048LL * 2048, 1024LL * 2048, 2048LL * 2048, 1.0f, 4, 8);

  // 5) out = fused @ w2^T + b2  (f32)         M=32768 N=1024 K=2048
  gemm256<false, true><<<4 * 128, 512, 0, stream>>>(
      fused, w2_16, d_out, w2b, 2048, 2048, 2048, 1024, 0, 0, 0, 1.0f, 4, 128);
}

// Round 3
// 646.457 us; speedup vs baseline: 1.2465x; 1.0057x over previous
//
#include <hip/hip_runtime.h>

typedef __attribute__((ext_vector_type(8))) short s16x8;
typedef __attribute__((ext_vector_type(8))) unsigned short u16x8;
typedef __attribute__((ext_vector_type(4))) unsigned short u16x4;
typedef __attribute__((ext_vector_type(4))) float f32x4;

__device__ inline float bf2f(unsigned short h) {
  union { unsigned int u; float f; } x; x.u = ((unsigned int)h) << 16; return x.f;
}
__device__ inline unsigned short f2bf(float f) {
  union { float f; unsigned int u; } x; x.f = f;
  unsigned int u = x.u;
  return (unsigned short)((u + 0x7fffu + ((u >> 16) & 1u)) >> 16);
}

// ---------------------------------------------------------------------------
// f32 -> bf16 cast with output row remap. cols = 1<<shift, multiple of 8.
// ---------------------------------------------------------------------------
__global__ __launch_bounds__(256) void cvt_bf16(const float* __restrict__ in,
                                                unsigned short* __restrict__ out,
                                                long long n, int shift, int ldo) {
  long long i = (long long)blockIdx.x * 256 + threadIdx.x;
  long long stride = (long long)gridDim.x * 256;
  long long nchunks = n >> 3;
  for (; i < nchunks; i += stride) {
    long long e = i << 3;
    long long r = e >> shift;
    int c = (int)(e & ((1LL << shift) - 1));
    const float4* p = (const float4*)(in + e);
    float4 f0 = p[0], f1 = p[1];
    u16x8 u;
    u[0] = f2bf(f0.x); u[1] = f2bf(f0.y); u[2] = f2bf(f0.z); u[3] = f2bf(f0.w);
    u[4] = f2bf(f1.x); u[5] = f2bf(f1.y); u[6] = f2bf(f1.z); u[7] = f2bf(f1.w);
    *(u16x8*)&out[r * (long long)ldo + c] = u;
  }
}

// ---------------------------------------------------------------------------
// per-batch bf16 transpose: in [rows][cols] -> out [cols][rows], 64x64 tiles
// ---------------------------------------------------------------------------
__global__ __launch_bounds__(256) void transpose_bf16(const unsigned short* __restrict__ in,
                                                      unsigned short* __restrict__ out,
                                                      int rows, int cols) {
  __shared__ unsigned short tile[64][72];
  long long zoff = (long long)blockIdx.z * rows * cols;
  const unsigned short* src = in + zoff;
  unsigned short* dst = out + zoff;
  int k0 = blockIdx.x * 64, d0 = blockIdx.y * 64;
  int t = threadIdx.x;
  int rr = t >> 4;
  int cc = (t & 15) * 4;
#pragma unroll
  for (int i = 0; i < 4; ++i) {
    int k = rr + i * 16;
    u16x4 v = *(const u16x4*)&src[(long long)(k0 + k) * cols + d0 + cc];
    *(u16x4*)&tile[k][cc] = v;
  }
  __syncthreads();
#pragma unroll
  for (int i = 0; i < 4; ++i) {
    int d = rr + i * 16;
    u16x4 v;
#pragma unroll
    for (int j = 0; j < 4; ++j) v[j] = tile[cc + j][d];
    *(u16x4*)&dst[(long long)(d0 + d) * rows + k0 + cc] = v;
  }
}

// ---------------------------------------------------------------------------
// row softmax over 2048 bf16 elements, in place; one wave per row
// ---------------------------------------------------------------------------
__global__ __launch_bounds__(256) void softmax_rows(unsigned short* __restrict__ P) {
  int w = threadIdx.x >> 6, l = threadIdx.x & 63;
  long long row = (long long)blockIdx.x * 4 + w;
  unsigned short* p = P + row * 2048;
  float v[32];
  float m = -1e30f;
#pragma unroll
  for (int c = 0; c < 4; ++c) {
    u16x8 u = *(const u16x8*)&p[c * 512 + l * 8];
#pragma unroll
    for (int j = 0; j < 8; ++j) { v[c * 8 + j] = bf2f(u[j]); m = fmaxf(m, v[c * 8 + j]); }
  }
#pragma unroll
  for (int s = 32; s; s >>= 1) m = fmaxf(m, __shfl_xor(m, s));
  float sum = 0.f;
#pragma unroll
  for (int i = 0; i < 32; ++i) { v[i] = __expf(v[i] - m); sum += v[i]; }
#pragma unroll
  for (int s = 32; s; s >>= 1) sum += __shfl_xor(sum, s);
  float r = 1.0f / sum;
#pragma unroll
  for (int c = 0; c < 4; ++c) {
    u16x8 u;
#pragma unroll
    for (int j = 0; j < 8; ++j) u[j] = f2bf(v[c * 8 + j] * r);
    *(u16x8*)&p[c * 512 + l * 8] = u;
  }
}

// ---------------------------------------------------------------------------
// 256x256 bf16 GEMM, B^T layout: C[m][n] = sum_k A[m][k]*Bt[n][k]
// Ring-4, register-double-buffered pipeline: BK=32, 8 waves (2m x 4n),
// LDS 128 KiB (4 slots x [A 16KB | B 16KB]). Per tile: one barrier, one
// counted vmcnt(4); all ds_read clusters issued under the previous MFMA
// burst (prefetch next tile's quad-A frags during quad0). 16x32-subtiled
// LDS with row-XOR swizzle; XCD-aware block swizzle; setprio around MFMA.
// Requires: M%256==0, N%256==0, K%32==0, K/32 even >=4, grid%8==0.
// ---------------------------------------------------------------------------
template <bool OUT_BF16, bool HAS_BIAS>
__global__ __launch_bounds__(512, 1) void gemm256(
    const unsigned short* __restrict__ A, const unsigned short* __restrict__ Bt,
    void* __restrict__ C, const float* __restrict__ bias,
    int K, int lda, int ldb, int ldc,
    long long sA, long long sB, long long sC, float scale,
    int gx, int gy) {
  __shared__ char lds[131072];
  const int t = threadIdx.x;
  const int l = t & 63, w = t >> 6;
  const int wm = w >> 2, wn = w & 3;

  // XCD-aware swizzle (launcher guarantees gridDim.x % 8 == 0)
  const int nwg = gridDim.x;
  const int id = blockIdx.x;
  const int sid = (id & 7) * (nwg >> 3) + (id >> 3);
  const int bx = sid % gx;
  const int rem = sid / gx;
  const int by = rem % gy;
  const int bz = rem / gy;

  A += (long long)bz * sA;
  Bt += (long long)bz * sB;
  const long long m0 = (long long)by * 256;
  const long long n0 = (long long)bx * 256;

  // staging addresses: linear LDS dest (t*16), inverse-swizzled global source
  const int srow = t >> 2;
  const int sk = (((t & 3) * 16) ^ (((t >> 3) & 3) << 4)) >> 1;
  const unsigned short* ga0 = A + (m0 + srow) * lda + sk;
  const unsigned short* ga1 = A + (m0 + 128 + srow) * lda + sk;
  const unsigned short* gb0 = Bt + (n0 + srow) * ldb + sk;
  const unsigned short* gb1 = Bt + (n0 + 128 + srow) * ldb + sk;
  const int Lt = t * 16;

  // fragment-read lane offset within a 1024B 16x32 subtile (swizzled)
  const int laneoff = (l & 15) * 64 + ((((l >> 4) * 16)) ^ (((l >> 1) & 3) << 4));

  f32x4 acc[8][4] = {};
  const int nt = K >> 5;

#define STAGE_A(tt)                                                                  \
  {                                                                                  \
    char* s_ = lds + (((tt) & 3) * 32768);                                           \
    long long ko_ = (long long)(tt) * 32;                                            \
    __builtin_amdgcn_global_load_lds(                                                \
        (const __attribute__((address_space(1))) void*)(ga0 + ko_),                  \
        (__attribute__((address_space(3))) void*)(s_ + Lt), 16, 0, 0);               \
    __builtin_amdgcn_global_load_lds(                                                \
        (const __attribute__((address_space(1))) void*)(ga1 + ko_),                  \
        (__attribute__((address_space(3))) void*)(s_ + 8192 + Lt), 16, 0, 0);        \
  }
#define STAGE_B(tt)                                                                  \
  {                                                                                  \
    char* s_ = lds + (((tt) & 3) * 32768) + 16384;                                   \
    long long ko_ = (long long)(tt) * 32;                                            \
    __builtin_amdgcn_global_load_lds(                                                \
        (const __attribute__((address_space(1))) void*)(gb0 + ko_),                  \
        (__attribute__((address_space(3))) void*)(s_ + Lt), 16, 0, 0);               \
    __builtin_amdgcn_global_load_lds(                                                \
        (const __attribute__((address_space(1))) void*)(gb1 + ko_),                  \
        (__attribute__((address_space(3))) void*)(s_ + 8192 + Lt), 16, 0, 0);        \
  }

  // prologue: stage tiles 0,1,2; retire tiles 0,1 (keep tile 2 in flight)
  STAGE_A(0); STAGE_B(0);
  STAGE_A(1); STAGE_B(1);
  STAGE_A(2); STAGE_B(2);
  asm volatile("s_waitcnt vmcnt(4)" ::: "memory");
  __builtin_amdgcn_s_barrier();

  s16x8 aA0[4], bA0[4], aA1[4], bA1[4];
  {
    const char* sa = lds + wm * 8192;
    const char* sb = lds + 16384 + wn * 4096;
#pragma unroll
    for (int m = 0; m < 4; ++m) aA0[m] = *(const s16x8*)(sa + m * 1024 + laneoff);
#pragma unroll
    for (int n = 0; n < 4; ++n) bA0[n] = *(const s16x8*)(sb + n * 1024 + laneoff);
  }

  // HALF(tt, CA, CB, PA, PB): process tile tt using frags CA/CB; prefetch
  // tile tt+1's quad-A frags into PA/PB under quad0's MFMA burst.
#define HALF(TT, CA, CB, PA, PB)                                                     \
  {                                                                                  \
    const int tt_ = (TT);                                                            \
    const char* sa_ = lds + ((tt_ & 3) * 32768) + wm * 8192;                         \
    if (tt_ + 3 < nt) STAGE_A(tt_ + 3);                                              \
    s16x8 fb_[4];                                                                    \
    _Pragma("unroll")                                                                \
    for (int m = 0; m < 4; ++m) fb_[m] = *(const s16x8*)(sa_ + (4 + m) * 1024 + laneoff); \
    if (tt_ + 3 < nt) STAGE_B(tt_ + 3);                                              \
    __builtin_amdgcn_s_setprio(1);                                                   \
    _Pragma("unroll")                                                                \
    for (int m = 0; m < 4; ++m)                                                      \
      _Pragma("unroll")                                                              \
      for (int n = 0; n < 4; ++n)                                                    \
        acc[m][n] = __builtin_amdgcn_mfma_f32_16x16x32_bf16(CA[m], CB[n], acc[m][n], 0, 0, 0); \
    __builtin_amdgcn_s_setprio(0);                                                   \
    if (tt_ + 1 < nt) {                                                              \
      const char* na_ = lds + (((tt_ + 1) & 3) * 32768) + wm * 8192;                 \
      const char* nb_ = lds + (((tt_ + 1) & 3) * 32768) + 16384 + wn * 4096;         \
      _Pragma("unroll")                                                              \
      for (int m = 0; m < 4; ++m) PA[m] = *(const s16x8*)(na_ + m * 1024 + laneoff); \
      _Pragma("unroll")                                                              \
      for (int n = 0; n < 4; ++n) PB[n] = *(const s16x8*)(nb_ + n * 1024 + laneoff); \
    }                                                                                \
    __builtin_amdgcn_s_setprio(1);                                                   \
    _Pragma("unroll")                                                                \
    for (int m = 0; m < 4; ++m)                                                      \
      _Pragma("unroll")                                                              \
      for (int n = 0; n < 4; ++n)                                                    \
        acc[4 + m][n] = __builtin_amdgcn_mfma_f32_16x16x32_bf16(fb_[m], CB[n], acc[4 + m][n], 0, 0, 0); \
    __builtin_amdgcn_s_setprio(0);                                                   \
    if (tt_ + 3 < nt) { asm volatile("s_waitcnt vmcnt(4)" ::: "memory"); }           \
    else              { asm volatile("s_waitcnt vmcnt(0)" ::: "memory"); }           \
    __builtin_amdgcn_s_barrier();                                                    \
  }

  for (int tt = 0; tt < nt; tt += 2) {
    HALF(tt, aA0, bA0, aA1, bA1);
    HALF(tt + 1, aA1, bA1, aA0, bA0);
  }
#undef HALF
#undef STAGE_A
#undef STAGE_B

  // ---- epilogue: C write ----
  const int cl = l & 15, rg = (l >> 4) * 4;
#pragma unroll
  for (int m = 0; m < 8; ++m) {
#pragma unroll
    for (int n = 0; n < 4; ++n) {
      long long col = n0 + wn * 64 + n * 16 + cl;
      long long row = m0 + wm * 128 + m * 16 + rg;
      float bb = HAS_BIAS ? bias[col] : 0.0f;
#pragma unroll
      for (int j = 0; j < 4; ++j) {
        float v = (acc[m][n][j] + bb) * scale;
        if (OUT_BF16)
          ((unsigned short*)C)[bz * sC + (row + j) * ldc + col] = f2bf(v);
        else
          ((float*)C)[bz * sC + (row + j) * ldc + col] = v;
      }
    }
  }
}

// ---------------------------------------------------------------------------
// Host launcher. ws layout (bytes):
//   fused  [32768][2048] bf16 : 0          .. 134217728   (bert | attn_out)
//   bfq    [32768][1024] bf16 : 134217728  .. 201326592
//   know16 [16][2048][1024]   : 201326592  .. 268435456
//   knowT  [16][1024][2048]   : 268435456  .. 335544320
//   w1_16  [1024][1024]       : 335544320  .. 337641472
//   w2_16  [1024][2048]       : 337641472  .. 341835776
// P (scores/probs) lives in d_out (bf16), then d_out is overwritten by the
// final fusion GEMM (f32).
// ---------------------------------------------------------------------------
extern "C" void kernel_launch(void* const* d_in, const int* in_sizes, int n_in,
                              void* d_out, int out_size, void* d_ws, size_t ws_size,
                              hipStream_t stream) {
  const float* bert = (const float*)d_in[0];
  const float* know = (const float*)d_in[1];
  const float* w1w  = (const float*)d_in[2];
  const float* w1b  = (const float*)d_in[3];
  const float* w2w  = (const float*)d_in[4];
  const float* w2b  = (const float*)d_in[5];

  char* ws = (char*)d_ws;
  unsigned short* fused  = (unsigned short*)(ws);
  unsigned short* bfq    = (unsigned short*)(ws + 134217728LL);
  unsigned short* know16 = (unsigned short*)(ws + 201326592LL);
  unsigned short* knowT  = (unsigned short*)(ws + 268435456LL);
  unsigned short* w1_16  = (unsigned short*)(ws + 335544320LL);
  unsigned short* w2_16  = (unsigned short*)(ws + 337641472LL);
  unsigned short* P      = (unsigned short*)d_out;

  // casts
  cvt_bf16<<<2048, 256, 0, stream>>>(bert, fused, 33554432LL, 10, 2048);
  cvt_bf16<<<2048, 256, 0, stream>>>(know, know16, 33554432LL, 10, 1024);
  cvt_bf16<<<512, 256, 0, stream>>>(w1w, w1_16, 1048576LL, 10, 1024);
  cvt_bf16<<<512, 256, 0, stream>>>(w2w, w2_16, 2097152LL, 11, 2048);
  transpose_bf16<<<dim3(32, 16, 16), 256, 0, stream>>>(know16, knowT, 2048, 1024);

  // 1) bfq = (bert @ w1^T + b1) / 32          M=32768 N=1024 K=1024
  gemm256<true, true><<<4 * 128, 512, 0, stream>>>(
      fused, w1_16, bfq, w1b, 1024, 2048, 1024, 1024, 0, 0, 0, 0.03125f, 4, 128);

  // 2) P = bfq @ know^T  (per batch)          M=2048 N=2048 K=1024
  gemm256<true, false><<<8 * 8 * 16, 512, 0, stream>>>(
      bfq, know16, P, nullptr, 1024, 1024, 1024, 2048,
      2048LL * 1024, 2048LL * 1024, 2048LL * 2048, 1.0f, 8, 8);

  // 3) softmax rows of P, in place
  softmax_rows<<<8192, 256, 0, stream>>>(P);

  // 4) attn_out = P @ know  (per batch)       M=2048 N=1024 K=2048
  gemm256<true, false><<<4 * 8 * 16, 512, 0, stream>>>(
      P, knowT, fused + 1024, nullptr, 2048, 2048, 2048, 2048,
      2048LL * 2048, 1024LL * 2048, 2048LL * 2048, 1.0f, 4, 8);

  // 5) out = fused @ w2^T + b2  (f32)         M=32768 N=1024 K=2048
  gemm256<false, true><<<4 * 128, 512, 0, stream>>>(
      fused, w2_16, d_out, w2b, 2048, 2048, 2048, 1024, 0, 0, 0, 1.0f, 4, 128);
}

// Round 4
// 645.552 us; speedup vs baseline: 1.2482x; 1.0014x over previous
//
#include <hip/hip_runtime.h>

typedef __attribute__((ext_vector_type(8))) short s16x8;
typedef __attribute__((ext_vector_type(8))) unsigned short u16x8;
typedef __attribute__((ext_vector_type(4))) unsigned short u16x4;
typedef __attribute__((ext_vector_type(4))) float f32x4;

__device__ inline float bf2f(unsigned short h) {
  union { unsigned int u; float f; } x; x.u = ((unsigned int)h) << 16; return x.f;
}
__device__ inline unsigned short f2bf(float f) {
  union { float f; unsigned int u; } x; x.f = f;
  unsigned int u = x.u;
  return (unsigned short)((u + 0x7fffu + ((u >> 16) & 1u)) >> 16);
}

// ---------------------------------------------------------------------------
// f32 -> bf16 cast with output row remap. cols = 1<<shift, multiple of 8.
// ---------------------------------------------------------------------------
__global__ __launch_bounds__(256) void cvt_bf16(const float* __restrict__ in,
                                                unsigned short* __restrict__ out,
                                                long long n, int shift, int ldo) {
  long long i = (long long)blockIdx.x * 256 + threadIdx.x;
  long long stride = (long long)gridDim.x * 256;
  long long nchunks = n >> 3;
  for (; i < nchunks; i += stride) {
    long long e = i << 3;
    long long r = e >> shift;
    int c = (int)(e & ((1LL << shift) - 1));
    const float4* p = (const float4*)(in + e);
    float4 f0 = p[0], f1 = p[1];
    u16x8 u;
    u[0] = f2bf(f0.x); u[1] = f2bf(f0.y); u[2] = f2bf(f0.z); u[3] = f2bf(f0.w);
    u[4] = f2bf(f1.x); u[5] = f2bf(f1.y); u[6] = f2bf(f1.z); u[7] = f2bf(f1.w);
    *(u16x8*)&out[r * (long long)ldo + c] = u;
  }
}

// ---------------------------------------------------------------------------
// per-batch bf16 transpose: in [rows][cols] -> out [cols][rows], 64x64 tiles
// ---------------------------------------------------------------------------
__global__ __launch_bounds__(256) void transpose_bf16(const unsigned short* __restrict__ in,
                                                      const unsigned short* __restrict__ unused,
                                                      unsigned short* __restrict__ out,
                                                      int rows, int cols) {
  __shared__ unsigned short tile[64][72];
  long long zoff = (long long)blockIdx.z * rows * cols;
  const unsigned short* src = in + zoff;
  unsigned short* dst = out + zoff;
  int k0 = blockIdx.x * 64, d0 = blockIdx.y * 64;
  int t = threadIdx.x;
  int rr = t >> 4;
  int cc = (t & 15) * 4;
#pragma unroll
  for (int i = 0; i < 4; ++i) {
    int k = rr + i * 16;
    u16x4 v = *(const u16x4*)&src[(long long)(k0 + k) * cols + d0 + cc];
    *(u16x4*)&tile[k][cc] = v;
  }
  __syncthreads();
#pragma unroll
  for (int i = 0; i < 4; ++i) {
    int d = rr + i * 16;
    u16x4 v;
#pragma unroll
    for (int j = 0; j < 4; ++j) v[j] = tile[cc + j][d];
    *(u16x4*)&dst[(long long)(d0 + d) * rows + k0 + cc] = v;
  }
}

// ---------------------------------------------------------------------------
// row softmax over 2048 bf16 elements, in place; one wave per row
// ---------------------------------------------------------------------------
__global__ __launch_bounds__(256) void softmax_rows(unsigned short* __restrict__ P) {
  int w = threadIdx.x >> 6, l = threadIdx.x & 63;
  long long row = (long long)blockIdx.x * 4 + w;
  unsigned short* p = P + row * 2048;
  float v[32];
  float m = -1e30f;
#pragma unroll
  for (int c = 0; c < 4; ++c) {
    u16x8 u = *(const u16x8*)&p[c * 512 + l * 8];
#pragma unroll
    for (int j = 0; j < 8; ++j) { v[c * 8 + j] = bf2f(u[j]); m = fmaxf(m, v[c * 8 + j]); }
  }
#pragma unroll
  for (int s = 32; s; s >>= 1) m = fmaxf(m, __shfl_xor(m, s));
  float sum = 0.f;
#pragma unroll
  for (int i = 0; i < 32; ++i) { v[i] = __expf(v[i] - m); sum += v[i]; }
#pragma unroll
  for (int s = 32; s; s >>= 1) sum += __shfl_xor(sum, s);
  float r = 1.0f / sum;
#pragma unroll
  for (int c = 0; c < 4; ++c) {
    u16x8 u;
#pragma unroll
    for (int j = 0; j < 8; ++j) u[j] = f2bf(v[c * 8 + j] * r);
    *(u16x8*)&p[c * 512 + l * 8] = u;
  }
}

// ---------------------------------------------------------------------------
// 256x256 bf16 GEMM, B^T layout: C[m][n] = sum_k A[m][k]*Bt[n][k]
// m201-style 8-phase schedule: BK=64, 8 waves (2m x 4n), LDS 128 KiB =
// 2 dbuf x [A(2 kslice slabs) | B(2 kslice slabs)], slab = 256 rows x 32 k.
// 4 phases per K-tile ({mhalf x kslice} quadrants of 16 MFMA); each phase:
// {ds_read frags, stage 1 half-tile (2 gload_lds), barrier, lgkmcnt(0),
// setprio(1), 16 MFMA, setprio(0), barrier}. Stagger: ph1 stages
// A-ksl1(t+1); ph2/3/4 stage B-ksl0/A-ksl0/B-ksl1 of (t+2). One counted
// vmcnt(6) checkpoint per K-tile (3 half-tiles stay in flight).
// Slab swizzle: phys = row*64 + ((kslot ^ ((row>>1)&3))<<4)  (<=2-way banks).
// Requires: M%256==0, N%256==0, K%64==0, K>=128, grid%8==0.
// ---------------------------------------------------------------------------
template <bool OUT_BF16, bool HAS_BIAS>
__global__ __launch_bounds__(512, 1) void gemm256(
    const unsigned short* __restrict__ A, const unsigned short* __restrict__ Bt,
    void* __restrict__ C, const float* __restrict__ bias,
    int K, int lda, int ldb, int ldc,
    long long sA, long long sB, long long sC, float scale,
    int gx, int gy) {
  __shared__ char lds[131072];
  const int t = threadIdx.x;
  const int l = t & 63, w = t >> 6;
  const int wm = w >> 2, wn = w & 3;

  // XCD-aware swizzle (launcher guarantees gridDim.x % 8 == 0)
  const int nwg = gridDim.x;
  const int id = blockIdx.x;
  const int sid = (id & 7) * (nwg >> 3) + (id >> 3);
  const int bx = sid % gx;
  const int rem = sid / gx;
  const int by = rem % gy;
  const int bz = rem / gy;

  A += (long long)bz * sA;
  Bt += (long long)bz * sB;
  const long long m0 = (long long)by * 256;
  const long long n0 = (long long)bx * 256;

  // staging: linear LDS dest (t*16 within 8KB), inverse-swizzled global src
  const int trow = t >> 2;                          // 0..127
  const int kl8 = ((t & 3) ^ ((t >> 3) & 3)) * 8;   // element offset in 32-k slab
  const unsigned short* gA = A + (m0 + trow) * lda + kl8;
  const unsigned short* gB = Bt + (n0 + trow) * ldb + kl8;
  const int Lt = t * 16;

  // fragment-read lane offset within a 16KB slab (row=(l&15), kslot=(l>>4))
  const int lo = (l & 15) * 64 + ((((l >> 4) ^ (((l & 15) >> 1) & 3))) << 4);

  f32x4 acc[8][4] = {};
  const int nt = K >> 6;  // BK=64 K-tiles

  // STAGE(mat, kt, ksl): stage one 16KB slab half (256 rows x 32 k) = 2 gloads
#define STAGE_A(KT, KSL)                                                             \
  {                                                                                  \
    char* d_ = lds + (((KT) & 1) * 65536) + ((KSL) * 16384);                         \
    const unsigned short* g_ = gA + (long long)(KT) * 64 + (KSL) * 32;               \
    __builtin_amdgcn_global_load_lds(                                                \
        (const __attribute__((address_space(1))) void*)g_,                           \
        (__attribute__((address_space(3))) void*)(d_ + Lt), 16, 0, 0);               \
    __builtin_amdgcn_global_load_lds(                                                \
        (const __attribute__((address_space(1))) void*)(g_ + 128 * lda),             \
        (__attribute__((address_space(3))) void*)(d_ + 8192 + Lt), 16, 0, 0);        \
  }
#define STAGE_B(KT, KSL)                                                             \
  {                                                                                  \
    char* d_ = lds + (((KT) & 1) * 65536) + 32768 + ((KSL) * 16384);                 \
    const unsigned short* g_ = gB + (long long)(KT) * 64 + (KSL) * 32;               \
    __builtin_amdgcn_global_load_lds(                                                \
        (const __attribute__((address_space(1))) void*)g_,                           \
        (__attribute__((address_space(3))) void*)(d_ + Lt), 16, 0, 0);               \
    __builtin_amdgcn_global_load_lds(                                                \
        (const __attribute__((address_space(1))) void*)(g_ + 128 * ldb),             \
        (__attribute__((address_space(3))) void*)(d_ + 8192 + Lt), 16, 0, 0);        \
  }

  // prologue: kt0 fully + kt1 {B-ksl0, A-ksl0, B-ksl1}; vmcnt(6) retires kt0.
  STAGE_A(0, 0); STAGE_A(0, 1); STAGE_B(0, 0); STAGE_B(0, 1);
  STAGE_B(1, 0); STAGE_A(1, 0); STAGE_B(1, 1);
  asm volatile("s_waitcnt vmcnt(6)" ::: "memory");
  __builtin_amdgcn_s_barrier();

  s16x8 af[4], bf[4];

#define READ_A(MH, KSL, CB)                                                          \
  _Pragma("unroll")                                                                  \
  for (int m_ = 0; m_ < 4; ++m_)                                                     \
    af[m_] = *(const s16x8*)((CB) + (KSL) * 16384 + wm * 8192 + ((MH) * 4 + m_) * 1024 + lo);
#define READ_B(KSL, CB)                                                              \
  _Pragma("unroll")                                                                  \
  for (int n_ = 0; n_ < 4; ++n_)                                                     \
    bf[n_] = *(const s16x8*)((CB) + 32768 + (KSL) * 16384 + wn * 4096 + n_ * 1024 + lo);
#define MFMA_Q(MH)                                                                   \
  __builtin_amdgcn_s_setprio(1);                                                     \
  _Pragma("unroll")                                                                  \
  for (int m_ = 0; m_ < 4; ++m_)                                                     \
    _Pragma("unroll")                                                                \
    for (int n_ = 0; n_ < 4; ++n_)                                                   \
      acc[(MH) * 4 + m_][n_] =                                                       \
          __builtin_amdgcn_mfma_f32_16x16x32_bf16(af[m_], bf[n_], acc[(MH) * 4 + m_][n_], 0, 0, 0); \
  __builtin_amdgcn_s_setprio(0);
#define BAR __builtin_amdgcn_s_barrier()
#define LGKM0 asm volatile("s_waitcnt lgkmcnt(0)" ::: "memory")

  for (int kt = 0; kt < nt; ++kt) {
    const char* cb = lds + (kt & 1) * 65536;
    const bool p1 = (kt + 1 < nt), p2 = (kt + 2 < nt);
    // phase 1: {mh0, ksl0}
    READ_B(0, cb); READ_A(0, 0, cb);
    if (p1) STAGE_A(kt + 1, 1);
    BAR; LGKM0; MFMA_Q(0); BAR;
    // phase 2: {mh1, ksl0}
    READ_A(1, 0, cb);
    if (p2) STAGE_B(kt + 2, 0);
    BAR; LGKM0; MFMA_Q(1); BAR;
    // phase 3: {mh0, ksl1}
    READ_B(1, cb); READ_A(0, 1, cb);
    if (p2) STAGE_A(kt + 2, 0);
    BAR; LGKM0; MFMA_Q(0); BAR;
    // phase 4: {mh1, ksl1}
    READ_A(1, 1, cb);
    if (p2) STAGE_B(kt + 2, 1);
    BAR; LGKM0; MFMA_Q(1);
    // checkpoint: retire through A-ksl1(kt+1); keep 3 half-tiles in flight
    if (p2)      asm volatile("s_waitcnt vmcnt(6)" ::: "memory");
    else         asm volatile("s_waitcnt vmcnt(0)" ::: "memory");
    BAR;
  }
#undef STAGE_A
#undef STAGE_B
#undef READ_A
#undef READ_B
#undef MFMA_Q
#undef BAR
#undef LGKM0

  // ---- epilogue: C write ----
  const int cl = l & 15, rg = (l >> 4) * 4;
#pragma unroll
  for (int m = 0; m < 8; ++m) {
#pragma unroll
    for (int n = 0; n < 4; ++n) {
      long long col = n0 + wn * 64 + n * 16 + cl;
      long long row = m0 + wm * 128 + m * 16 + rg;
      float bb = HAS_BIAS ? bias[col] : 0.0f;
#pragma unroll
      for (int j = 0; j < 4; ++j) {
        float v = (acc[m][n][j] + bb) * scale;
        if (OUT_BF16)
          ((unsigned short*)C)[bz * sC + (row + j) * ldc + col] = f2bf(v);
        else
          ((float*)C)[bz * sC + (row + j) * ldc + col] = v;
      }
    }
  }
}

// ---------------------------------------------------------------------------
// Host launcher. ws layout (bytes):
//   fused  [32768][2048] bf16 : 0          .. 134217728   (bert | attn_out)
//   bfq    [32768][1024] bf16 : 134217728  .. 201326592
//   know16 [16][2048][1024]   : 201326592  .. 268435456
//   knowT  [16][1024][2048]   : 268435456  .. 335544320
//   w1_16  [1024][1024]       : 335544320  .. 337641472
//   w2_16  [1024][2048]       : 337641472  .. 341835776
// P (scores/probs) lives in d_out (bf16), then d_out is overwritten by the
// final fusion GEMM (f32).
// ---------------------------------------------------------------------------
extern "C" void kernel_launch(void* const* d_in, const int* in_sizes, int n_in,
                              void* d_out, int out_size, void* d_ws, size_t ws_size,
                              hipStream_t stream) {
  const float* bert = (const float*)d_in[0];
  const float* know = (const float*)d_in[1];
  const float* w1w  = (const float*)d_in[2];
  const float* w1b  = (const float*)d_in[3];
  const float* w2w  = (const float*)d_in[4];
  const float* w2b  = (const float*)d_in[5];

  char* ws = (char*)d_ws;
  unsigned short* fused  = (unsigned short*)(ws);
  unsigned short* bfq    = (unsigned short*)(ws + 134217728LL);
  unsigned short* know16 = (unsigned short*)(ws + 201326592LL);
  unsigned short* knowT  = (unsigned short*)(ws + 268435456LL);
  unsigned short* w1_16  = (unsigned short*)(ws + 335544320LL);
  unsigned short* w2_16  = (unsigned short*)(ws + 337641472LL);
  unsigned short* P      = (unsigned short*)d_out;

  // casts
  cvt_bf16<<<2048, 256, 0, stream>>>(bert, fused, 33554432LL, 10, 2048);
  cvt_bf16<<<2048, 256, 0, stream>>>(know, know16, 33554432LL, 10, 1024);
  cvt_bf16<<<512, 256, 0, stream>>>(w1w, w1_16, 1048576LL, 10, 1024);
  cvt_bf16<<<512, 256, 0, stream>>>(w2w, w2_16, 2097152LL, 11, 2048);
  transpose_bf16<<<dim3(32, 16, 16), 256, 0, stream>>>(know16, nullptr, knowT, 2048, 1024);

  // 1) bfq = (bert @ w1^T + b1) / 32          M=32768 N=1024 K=1024
  gemm256<true, true><<<4 * 128, 512, 0, stream>>>(
      fused, w1_16, bfq, w1b, 1024, 2048, 1024, 1024, 0, 0, 0, 0.03125f, 4, 128);

  // 2) P = bfq @ know^T  (per batch)          M=2048 N=2048 K=1024
  gemm256<true, false><<<8 * 8 * 16, 512, 0, stream>>>(
      bfq, know16, P, nullptr, 1024, 1024, 1024, 2048,
      2048LL * 1024, 2048LL * 1024, 2048LL * 2048, 1.0f, 8, 8);

  // 3) softmax rows of P, in place
  softmax_rows<<<8192, 256, 0, stream>>>(P);

  // 4) attn_out = P @ know  (per batch)       M=2048 N=1024 K=2048
  gemm256<true, false><<<4 * 8 * 16, 512, 0, stream>>>(
      P, knowT, fused + 1024, nullptr, 2048, 2048, 2048, 2048,
      2048LL * 2048, 1024LL * 2048, 2048LL * 2048, 1.0f, 4, 8);

  // 5) out = fused @ w2^T + b2  (f32)         M=32768 N=1024 K=2048
  gemm256<false, true><<<4 * 128, 512, 0, stream>>>(
      fused, w2_16, d_out, w2b, 2048, 2048, 2048, 1024, 0, 0, 0, 1.0f, 4, 128);
}

// Round 6
// 625.110 us; speedup vs baseline: 1.2891x; 1.0327x over previous
//
#include <hip/hip_runtime.h>

typedef __attribute__((ext_vector_type(8))) short s16x8;
typedef __attribute__((ext_vector_type(8))) unsigned short u16x8;
typedef __attribute__((ext_vector_type(4))) unsigned short u16x4;
typedef __attribute__((ext_vector_type(4))) float f32x4;

__device__ inline float bf2f(unsigned short h) {
  union { unsigned int u; float f; } x; x.u = ((unsigned int)h) << 16; return x.f;
}
__device__ inline unsigned short f2bf(float f) {
  union { float f; unsigned int u; } x; x.f = f;
  unsigned int u = x.u;
  return (unsigned short)((u + 0x7fffu + ((u >> 16) & 1u)) >> 16);
}

// ---------------------------------------------------------------------------
// f32 -> bf16 cast with output row remap. cols = 1<<shift, multiple of 8.
// ---------------------------------------------------------------------------
__global__ __launch_bounds__(256) void cvt_bf16(const float* __restrict__ in,
                                                unsigned short* __restrict__ out,
                                                long long n, int shift, int ldo) {
  long long i = (long long)blockIdx.x * 256 + threadIdx.x;
  long long stride = (long long)gridDim.x * 256;
  long long nchunks = n >> 3;
  for (; i < nchunks; i += stride) {
    long long e = i << 3;
    long long r = e >> shift;
    int c = (int)(e & ((1LL << shift) - 1));
    const float4* p = (const float4*)(in + e);
    float4 f0 = p[0], f1 = p[1];
    u16x8 u;
    u[0] = f2bf(f0.x); u[1] = f2bf(f0.y); u[2] = f2bf(f0.z); u[3] = f2bf(f0.w);
    u[4] = f2bf(f1.x); u[5] = f2bf(f1.y); u[6] = f2bf(f1.z); u[7] = f2bf(f1.w);
    *(u16x8*)&out[r * (long long)ldo + c] = u;
  }
}

// ---------------------------------------------------------------------------
// per-batch fused cast+transpose: in f32 [rows][cols] -> out_n bf16 [rows][cols]
// AND out_t bf16 [cols][rows]. 64x64 tiles, reads f32 input exactly once.
// ---------------------------------------------------------------------------
__global__ __launch_bounds__(256) void cvt_transpose(const float* __restrict__ in,
                                                     unsigned short* __restrict__ out_n,
                                                     unsigned short* __restrict__ out_t,
                                                     int rows, int cols) {
  __shared__ unsigned short tile[64][72];
  long long zoff = (long long)blockIdx.z * rows * cols;
  const float* src = in + zoff;
  unsigned short* dstn = out_n + zoff;
  unsigned short* dstt = out_t + zoff;
  int k0 = blockIdx.x * 64, d0 = blockIdx.y * 64;
  int t = threadIdx.x;
  int rr = t >> 4;
  int cc = (t & 15) * 4;
#pragma unroll
  for (int i = 0; i < 4; ++i) {
    int k = rr + i * 16;
    float4 v = *(const float4*)&src[(long long)(k0 + k) * cols + d0 + cc];
    u16x4 u;
    u[0] = f2bf(v.x); u[1] = f2bf(v.y); u[2] = f2bf(v.z); u[3] = f2bf(v.w);
    *(u16x4*)&dstn[(long long)(k0 + k) * cols + d0 + cc] = u;
    *(u16x4*)&tile[k][cc] = u;
  }
  __syncthreads();
#pragma unroll
  for (int i = 0; i < 4; ++i) {
    int d = rr + i * 16;
    u16x4 v;
#pragma unroll
    for (int j = 0; j < 4; ++j) v[j] = tile[cc + j][d];
    *(u16x4*)&dstt[(long long)(d0 + d) * rows + k0 + cc] = v;
  }
}

// ---------------------------------------------------------------------------
// rinv[i] = 1 / sum_{b<8} part[i*8+b]
// ---------------------------------------------------------------------------
__global__ __launch_bounds__(256) void rowsum_inv(const float* __restrict__ part,
                                                  float* __restrict__ rinv, int nrows) {
  int i = blockIdx.x * 256 + threadIdx.x;
  if (i < nrows) {
    const float* p = part + (long long)i * 8;
    float s = 0.f;
#pragma unroll
    for (int k = 0; k < 8; ++k) s += p[k];
    rinv[i] = 1.0f / s;
  }
}

// ---------------------------------------------------------------------------
// 256x256 bf16 GEMM, B^T layout (R4 8-phase schedule).
// EXP_SM epilogue: write exp(acc) and per-row partial sums to `part`
// (assumes gx==8, HAS_BIAS=false, scale=1). ROWSCALE epilogue: multiply
// output rows by rinv[bz*2048+row].
// ---------------------------------------------------------------------------
template <bool OUT_BF16, bool HAS_BIAS, bool EXP_SM, bool ROWSCALE>
__global__ __launch_bounds__(512, 1) void gemm256(
    const unsigned short* __restrict__ A, const unsigned short* __restrict__ Bt,
    void* __restrict__ C, const float* __restrict__ bias,
    int K, int lda, int ldb, int ldc,
    long long sA, long long sB, long long sC, float scale,
    int gx, int gy, float* __restrict__ part, const float* __restrict__ rinv) {
  __shared__ char lds[131072];
  const int t = threadIdx.x;
  const int l = t & 63, w = t >> 6;
  const int wm = w >> 2, wn = w & 3;

  const int nwg = gridDim.x;
  const int id = blockIdx.x;
  const int sid = (id & 7) * (nwg >> 3) + (id >> 3);
  const int bx = sid % gx;
  const int rem = sid / gx;
  const int by = rem % gy;
  const int bz = rem / gy;

  A += (long long)bz * sA;
  Bt += (long long)bz * sB;
  const long long m0 = (long long)by * 256;
  const long long n0 = (long long)bx * 256;

  const int trow = t >> 2;
  const int kl8 = ((t & 3) ^ ((t >> 3) & 3)) * 8;
  const unsigned short* gA = A + (m0 + trow) * lda + kl8;
  const unsigned short* gB = Bt + (n0 + trow) * ldb + kl8;
  const int Lt = t * 16;

  const int lo = (l & 15) * 64 + ((((l >> 4) ^ (((l & 15) >> 1) & 3))) << 4);

  f32x4 acc[8][4] = {};
  const int nt = K >> 6;

#define STAGE_A(KT, KSL)                                                             \
  {                                                                                  \
    char* d_ = lds + (((KT) & 1) * 65536) + ((KSL) * 16384);                         \
    const unsigned short* g_ = gA + (long long)(KT) * 64 + (KSL) * 32;               \
    __builtin_amdgcn_global_load_lds(                                                \
        (const __attribute__((address_space(1))) void*)g_,                           \
        (__attribute__((address_space(3))) void*)(d_ + Lt), 16, 0, 0);               \
    __builtin_amdgcn_global_load_lds(                                                \
        (const __attribute__((address_space(1))) void*)(g_ + 128 * lda),             \
        (__attribute__((address_space(3))) void*)(d_ + 8192 + Lt), 16, 0, 0);        \
  }
#define STAGE_B(KT, KSL)                                                             \
  {                                                                                  \
    char* d_ = lds + (((KT) & 1) * 65536) + 32768 + ((KSL) * 16384);                 \
    const unsigned short* g_ = gB + (long long)(KT) * 64 + (KSL) * 32;               \
    __builtin_amdgcn_global_load_lds(                                                \
        (const __attribute__((address_space(1))) void*)g_,                           \
        (__attribute__((address_space(3))) void*)(d_ + Lt), 16, 0, 0);               \
    __builtin_amdgcn_global_load_lds(                                                \
        (const __attribute__((address_space(1))) void*)(g_ + 128 * ldb),             \
        (__attribute__((address_space(3))) void*)(d_ + 8192 + Lt), 16, 0, 0);        \
  }

  STAGE_A(0, 0); STAGE_A(0, 1); STAGE_B(0, 0); STAGE_B(0, 1);
  STAGE_B(1, 0); STAGE_A(1, 0); STAGE_B(1, 1);
  asm volatile("s_waitcnt vmcnt(6)" ::: "memory");
  __builtin_amdgcn_s_barrier();

  s16x8 af[4], bf[4];

#define READ_A(MH, KSL, CB)                                                          \
  _Pragma("unroll")                                                                  \
  for (int m_ = 0; m_ < 4; ++m_)                                                     \
    af[m_] = *(const s16x8*)((CB) + (KSL) * 16384 + wm * 8192 + ((MH) * 4 + m_) * 1024 + lo);
#define READ_B(KSL, CB)                                                              \
  _Pragma("unroll")                                                                  \
  for (int n_ = 0; n_ < 4; ++n_)                                                     \
    bf[n_] = *(const s16x8*)((CB) + 32768 + (KSL) * 16384 + wn * 4096 + n_ * 1024 + lo);
#define MFMA_Q(MH)                                                                   \
  __builtin_amdgcn_s_setprio(1);                                                     \
  _Pragma("unroll")                                                                  \
  for (int m_ = 0; m_ < 4; ++m_)                                                     \
    _Pragma("unroll")                                                                \
    for (int n_ = 0; n_ < 4; ++n_)                                                   \
      acc[(MH) * 4 + m_][n_] =                                                       \
          __builtin_amdgcn_mfma_f32_16x16x32_bf16(af[m_], bf[n_], acc[(MH) * 4 + m_][n_], 0, 0, 0); \
  __builtin_amdgcn_s_setprio(0);
#define BAR __builtin_amdgcn_s_barrier()
#define LGKM0 asm volatile("s_waitcnt lgkmcnt(0)" ::: "memory")

  for (int kt = 0; kt < nt; ++kt) {
    const char* cb = lds + (kt & 1) * 65536;
    const bool p1 = (kt + 1 < nt), p2 = (kt + 2 < nt);
    READ_B(0, cb); READ_A(0, 0, cb);
    if (p1) STAGE_A(kt + 1, 1);
    BAR; LGKM0; MFMA_Q(0); BAR;
    READ_A(1, 0, cb);
    if (p2) STAGE_B(kt + 2, 0);
    BAR; LGKM0; MFMA_Q(1); BAR;
    READ_B(1, cb); READ_A(0, 1, cb);
    if (p2) STAGE_A(kt + 2, 0);
    BAR; LGKM0; MFMA_Q(0); BAR;
    READ_A(1, 1, cb);
    if (p2) STAGE_B(kt + 2, 1);
    BAR; LGKM0; MFMA_Q(1);
    if (p2)      asm volatile("s_waitcnt vmcnt(6)" ::: "memory");
    else         asm volatile("s_waitcnt vmcnt(0)" ::: "memory");
    BAR;
  }
#undef STAGE_A
#undef STAGE_B
#undef READ_A
#undef READ_B
#undef MFMA_Q
#undef BAR
#undef LGKM0

  const int cl = l & 15, rg = (l >> 4) * 4;

  if (EXP_SM) {
    // transform acc -> exp(acc); per-row partial sums of this block's 256 cols
    float* pl = (float*)lds;  // [4 wn][256 rows]; K-loop LDS use is done
#pragma unroll
    for (int m = 0; m < 8; ++m) {
#pragma unroll
      for (int j = 0; j < 4; ++j) {
        float s = 0.f;
#pragma unroll
        for (int n = 0; n < 4; ++n) {
          float e = __expf(acc[m][n][j]);
          acc[m][n][j] = e;
          s += e;
        }
        s += __shfl_xor(s, 1); s += __shfl_xor(s, 2);
        s += __shfl_xor(s, 4); s += __shfl_xor(s, 8);
        if (cl == 0) pl[wn * 256 + wm * 128 + m * 16 + rg + j] = s;
      }
    }
    __syncthreads();
    if (t < 256) {
      float s = pl[t] + pl[256 + t] + pl[512 + t] + pl[768 + t];
      part[((long long)bz * 2048 + m0 + t) * 8 + bx] = s;
    }
  }

#pragma unroll
  for (int m = 0; m < 8; ++m) {
    long long row = m0 + wm * 128 + m * 16 + rg;
    float rv[4];
    if (ROWSCALE) {
#pragma unroll
      for (int j = 0; j < 4; ++j) rv[j] = rinv[(long long)bz * 2048 + row + j];
    }
#pragma unroll
    for (int n = 0; n < 4; ++n) {
      long long col = n0 + wn * 64 + n * 16 + cl;
      float bb = HAS_BIAS ? bias[col] : 0.0f;
#pragma unroll
      for (int j = 0; j < 4; ++j) {
        float v = EXP_SM ? acc[m][n][j] : (acc[m][n][j] + bb) * scale;
        if (ROWSCALE) v *= rv[j];
        if (OUT_BF16)
          ((unsigned short*)C)[bz * sC + (row + j) * ldc + col] = f2bf(v);
        else
          ((float*)C)[bz * sC + (row + j) * ldc + col] = v;
      }
    }
  }
}

// ---------------------------------------------------------------------------
// Host launcher. ws layout (bytes):
//   fused  [32768][2048] bf16 : 0          .. 134217728   (bert | attn_out)
//   bfq    [32768][1024] bf16 : 134217728  .. 201326592
//   know16 [16][2048][1024]   : 201326592  .. 268435456
//   knowT  [16][1024][2048]   : 268435456  .. 335544320
//   w1_16  [1024][1024]       : 335544320  .. 337641472
//   w2_16  [1024][2048]       : 337641472  .. 341835776
//   part   [32768][8] f32     : 341835776  .. 342884352
//   rinv   [32768] f32        : 342884352  .. 343015424
// E = exp(scores) lives in d_out (bf16), then d_out is overwritten by the
// final fusion GEMM (f32). Softmax normalization is folded into GEMM4's
// output rows (row-constant factor commutes with the PV reduction).
// ---------------------------------------------------------------------------
extern "C" void kernel_launch(void* const* d_in, const int* in_sizes, int n_in,
                              void* d_out, int out_size, void* d_ws, size_t ws_size,
                              hipStream_t stream) {
  const float* bert = (const float*)d_in[0];
  const float* know = (const float*)d_in[1];
  const float* w1w  = (const float*)d_in[2];
  const float* w1b  = (const float*)d_in[3];
  const float* w2w  = (const float*)d_in[4];
  const float* w2b  = (const float*)d_in[5];

  char* ws = (char*)d_ws;
  unsigned short* fused  = (unsigned short*)(ws);
  unsigned short* bfq    = (unsigned short*)(ws + 134217728LL);
  unsigned short* know16 = (unsigned short*)(ws + 201326592LL);
  unsigned short* knowT  = (unsigned short*)(ws + 268435456LL);
  unsigned short* w1_16  = (unsigned short*)(ws + 335544320LL);
  unsigned short* w2_16  = (unsigned short*)(ws + 337641472LL);
  float*          part   = (float*)(ws + 341835776LL);
  float*          rinv   = (float*)(ws + 342884352LL);
  unsigned short* P      = (unsigned short*)d_out;

  // casts + fused know cast/transpose
  cvt_bf16<<<2048, 256, 0, stream>>>(bert, fused, 33554432LL, 10, 2048);
  cvt_bf16<<<512, 256, 0, stream>>>(w1w, w1_16, 1048576LL, 10, 1024);
  cvt_bf16<<<512, 256, 0, stream>>>(w2w, w2_16, 2097152LL, 11, 2048);
  cvt_transpose<<<dim3(32, 16, 16), 256, 0, stream>>>(know, know16, knowT, 2048, 1024);

  // 1) bfq = (bert @ w1^T + b1) / 32          M=32768 N=1024 K=1024
  gemm256<true, true, false, false><<<4 * 128, 512, 0, stream>>>(
      fused, w1_16, bfq, w1b, 1024, 2048, 1024, 1024, 0, 0, 0, 0.03125f, 4, 128,
      nullptr, nullptr);

  // 2) E = exp(bfq @ know^T) + row partial sums   M=2048 N=2048 K=1024
  gemm256<true, false, true, false><<<8 * 8 * 16, 512, 0, stream>>>(
      bfq, know16, P, nullptr, 1024, 1024, 1024, 2048,
      2048LL * 1024, 2048LL * 1024, 2048LL * 2048, 1.0f, 8, 8,
      part, nullptr);

  // 3) rinv = 1/rowsum
  rowsum_inv<<<128, 256, 0, stream>>>(part, rinv, 32768);

  // 4) attn_out = (E @ know) * rinv[row]      M=2048 N=1024 K=2048
  gemm256<true, false, false, true><<<4 * 8 * 16, 512, 0, stream>>>(
      P, knowT, fused + 1024, nullptr, 2048, 2048, 2048, 2048,
      2048LL * 2048, 1024LL * 2048, 2048LL * 2048, 1.0f, 4, 8,
      nullptr, rinv);

  // 5) out = fused @ w2^T + b2  (f32)         M=32768 N=1024 K=2048
  gemm256<false, true, false, false><<<4 * 128, 512, 0, stream>>>(
      fused, w2_16, d_out, w2b, 2048, 2048, 2048, 1024, 0, 0, 0, 1.0f, 4, 128,
      nullptr, nullptr);
}